// Round 7
// baseline (293.904 us; speedup 1.0000x reference)
//
#include <hip/hip_runtime.h>
#include <hip/hip_bf16.h>
#include <math.h>

// Sizes fixed by the reference setup: B=512, F=512, max_depth=8 -> S=255 splits, N=511 nodes, NC=21.
#define BATCH 512
#define FDIM  512
#define NSPL  255
#define NNOD  511
#define NC    21

// NOTE (round-3/5 post-mortems): the scan's merge dynamics depend on EXACT
// bit-level ties. Changes that broke them (full 512-iteration blowup, ~900us):
//   (1) duplicating/rewriting f64 blend expressions (round 3);
//   (2) replacing __shfl_xor butterflies with DPP/swizzle (round 5).
// Changes proven bit-safe (round 6): textually-identical code recompiled in a
// different kernel; memory-path-only changes; downstream-of-scan changes.
// This round: all phases fused into ONE persistent kernel (k_mega) with custom
// grid barriers; every phase body is a TEXTUAL COPY of the validated round-6
// kernels. Scan's __syncthreads -> __threadfence_block (single-wave, ordering
// only, FP sequence untouched).

// ---------------------------------------------------------------------------
// Grid barrier: hierarchical, state zeroed by hipMemsetAsync before launch.
// slot(i) = bar + i*32 (128 B apart). cnt: slots 1..32 (k*8+cell), root:
// 33..36, gen: 37..40. Grid is fixed at 512 blocks -> 64 arrivals per cell.
// ---------------------------------------------------------------------------
__device__ __forceinline__ unsigned* bslot(unsigned* bar, int i) { return bar + (size_t)i * 32; }

__device__ __forceinline__ void grid_bar(unsigned* bar, int k, int bid, int tid) {
  __syncthreads();                       // drains each thread's stores (vmcnt) pre-barrier
  if (tid == 0) {
    __threadfence();
    unsigned cell = (unsigned)(bid & 7);
    unsigned v = __hip_atomic_fetch_add(bslot(bar, 1 + k * 8 + (int)cell), 1u,
                                        __ATOMIC_ACQ_REL, __HIP_MEMORY_SCOPE_AGENT);
    if (v == 63u) {
      unsigned r = __hip_atomic_fetch_add(bslot(bar, 33 + k), 1u,
                                          __ATOMIC_ACQ_REL, __HIP_MEMORY_SCOPE_AGENT);
      if (r == 7u)
        __hip_atomic_store(bslot(bar, 37 + k), 1u, __ATOMIC_RELEASE, __HIP_MEMORY_SCOPE_AGENT);
    }
    while (__hip_atomic_load(bslot(bar, 37 + k), __ATOMIC_ACQUIRE, __HIP_MEMORY_SCOPE_AGENT) != 1u)
      __builtin_amdgcn_s_sleep(2);
    __threadfence();
  }
  __syncthreads();
}

// ---------------------------------------------------------------------------
// q_node walk (same bit pattern everywhere)
// ---------------------------------------------------------------------------
__device__ __forceinline__ float qnode_walk(const float* __restrict__ qsT, int n, int b) {
  float q = 1.0f;
  int a = n;
  while (a > 0) {
    int p = (a - 1) >> 1;
    float v = qsT[p * BATCH + b];
    q = fminf(q, (a & 1) ? -v : v);
    a = p;
  }
  return q;
}

// ---------------------------------------------------------------------------
// THE MEGA KERNEL. 512 blocks x 256 threads. Phases separated by grid_bar.
// LDS: one 53168-B arena re-sliced per phase (scan layout is the largest).
// __launch_bounds__(256,2): VGPR<=256 -> >=2 blocks/CU -> all 512 co-resident.
// ---------------------------------------------------------------------------
__global__ __launch_bounds__(256, 2) void k_mega(
    const float* __restrict__ x, const float* __restrict__ W,
    const float* __restrict__ bias,
    float* __restrict__ partial, float* __restrict__ qsT,
    float* __restrict__ ga, double* __restrict__ agrp0,
    double* __restrict__ a_node, float* __restrict__ out,
    unsigned* __restrict__ bar, int fpc, int nchunks) {
  __shared__ __align__(16) char smraw[53168];
  const int tid = threadIdx.x;
  const int bid = blockIdx.x;

  // ===== P1: split-K GEMM (textual copy of validated k_qgemm) =====
  if (bid < 32 * nchunks) {
    float* Ws = (float*)smraw;
    float* xT = Ws + 64 * 68;
    const int s0 = (bid & 3) * 64;
    const int b0 = ((bid >> 2) & 7) * 64;
    const int bz = bid >> 5;
    const int f0 = bz * fpc;
    const int sx = tid & 15;
    const int by = tid >> 4;
    float acc[4][4];
#pragma unroll
    for (int i = 0; i < 4; ++i)
#pragma unroll
      for (int j = 0; j < 4; ++j) acc[i][j] = 0.f;

    for (int fc = f0; fc < f0 + fpc; fc += 64) {
      {
        int si = tid & 63, fr = tid >> 6;
#pragma unroll
        for (int r = 0; r < 16; ++r) {
          int fi = fr + r * 4;
          int s = s0 + si;
          Ws[fi * 68 + si] = (s < NSPL) ? W[(fc + fi) * NSPL + s] : 0.f;
        }
        int j = tid & 63, ir = tid >> 6;
#pragma unroll
        for (int r = 0; r < 16; ++r) {
          int i = ir + r * 4;
          xT[j * 68 + i] = x[(b0 + i) * FDIM + (fc + j)];
        }
      }
      __syncthreads();
#pragma unroll 8
      for (int f = 0; f < 64; ++f) {
        float4 av = *(const float4*)&Ws[f * 68 + sx * 4];
        float4 xv = *(const float4*)&xT[f * 68 + by * 4];
        const float a4[4] = {av.x, av.y, av.z, av.w};
        const float x4[4] = {xv.x, xv.y, xv.z, xv.w};
#pragma unroll
        for (int i = 0; i < 4; ++i)
#pragma unroll
          for (int j = 0; j < 4; ++j) acc[i][j] += a4[i] * x4[j];
      }
      __syncthreads();
    }

    float* pout = partial + (size_t)bz * (256 * BATCH);
#pragma unroll
    for (int i = 0; i < 4; ++i) {
      int s = s0 + sx * 4 + i;
      if (s < NSPL) {
        float4 v = make_float4(acc[i][0], acc[i][1], acc[i][2], acc[i][3]);
        *(float4*)&pout[s * BATCH + b0 + by * 4] = v;
      }
    }
  }
  grid_bar(bar, 0, bid, tid);

  // ===== P2: reduce (textual copy of validated k_qreduce) =====
  if (bid < 510) {
    int idx = bid * 256 + tid;
    if (idx < NSPL * BATCH) {
      int s = idx >> 9;
      float v = 0.f;
      for (int c = 0; c < nchunks; ++c) v += partial[(size_t)c * (256 * BATCH) + idx];
      qsT[idx] = v + bias[s];
    }
  }
  grid_bar(bar, 1, bid, tid);

  // ===== P3: g_a + agrp0 (textual copy of validated fused k_ga) =====
  if (bid < NNOD) {
    const int n = bid;
    float* qs = (float*)smraw;                              // 2048 B
    double (*part)[NC] = (double (*)[NC])(smraw + 2048);    // 672 B
    float* gaRow = (float*)(smraw + 2720);                  // 84 B
#pragma unroll
    for (int rep = 0; rep < 2; ++rep) {
      int b = tid + rep * 256;
      qs[b] = qnode_walk(qsT, n, b);
    }
    __syncthreads();
    if (tid < 4 * NC) {
      int c = tid % NC, chunk = tid / NC;
      double ac = 0.05 * (double)c;
      double ssum = 0.0;
      int b0 = chunk * 128;
      for (int b = b0; b < b0 + 128; ++b) {
        float qh = qs[b] + 0.5f;          // f32 add (NumPy scalar promotion keeps f32)
        double dqh = (double)qh;
        if (ac <= dqh) { double d = ac - dqh; ssum += d * d; }
      }
      part[chunk][c] = ssum;
    }
    __syncthreads();
    if (tid < NC) {
      double ac = 0.05 * (double)tid;
      double ssum = ((part[0][tid] + part[1][tid]) + part[2][tid]) + part[3][tid];
      float gv = (float)(0.5 * ac * ac + 0.5 * ssum);
      ga[n * NC + tid] = gv;
      gaRow[tid] = gv;
    }
    __syncthreads();
    if (tid == 0) {
      double z[NC], m = -1e300;
#pragma unroll
      for (int c = 0; c < NC; ++c) { z[c] = -100.0 * (double)gaRow[c]; m = fmax(m, z[c]); }
      double S = 0.0;
#pragma unroll
      for (int c = 0; c < NC; ++c) { z[c] = exp(z[c] - m); S += z[c]; }
      double A = 0.0;
#pragma unroll
      for (int c = 0; c < NC; ++c) A += (0.05 * (double)c) * (z[c] / S);
      agrp0[n] = A;
    }
  }
  grid_bar(bar, 2, bid, tid);

  // ===== P4: scan on block 0 / wave 0 (textual copy of validated k_scan;
  // __syncthreads -> __threadfence_block: single-wave, ordering only).
  // Concurrently blocks 1..511 precompute their k_out q-walks (scan-independent).
  float q0 = 0.f, q1 = 0.f;
  if (bid == 0) {
    if (tid < 64) {
      float* gaS = (float*)smraw;                     // 42924 B
      double* agrp = (double*)(smraw + 42928);        // 4096 B
      double* anode = (double*)(smraw + 47024);       // 4096 B
      float* kfS = (float*)(smraw + 51120);           // 2048 B
      const int lane = tid;
      {
        const float4* src = (const float4*)ga;
        float4* dst = (float4*)gaS;
        const int n4 = (NNOD * NC) / 4;               // 2682
#pragma unroll 4
        for (int i = lane; i < n4; i += 64) dst[i] = src[i];
        if (lane < (NNOD * NC) - n4 * 4) gaS[n4 * 4 + lane] = ga[n4 * 4 + lane];
      }
      for (int i = lane; i < 512; i += 64) {
        agrp[i] = (i < NNOD) ? agrp0[i] : 0.0;
        anode[i] = 0.0;
        kfS[i] = 0.0f;
      }
      __threadfence_block();

      int t = 0, p = 0;
      double areg[8];
      int iter = 0;
      for (;;) {
        if (iter > 0) {
          int j = lane >> 5, c = lane & 31;
          int g = j ? p : t;
          double z = -1e300;
          if (c < NC) {
            double acc = (1.0 - (double)kfS[g]) * (double)gaS[g * NC + c];
            int l = 2 * g + 1, r = 2 * g + 2;
            if (l < NNOD) acc = acc + (double)kfS[l] * (double)gaS[l * NC + c];
            if (r < NNOD) acc = acc + (double)kfS[r] * (double)gaS[r * NC + c];
            z = -100.0 * acc;
          }
          double m = z;
#pragma unroll
          for (int off = 16; off >= 1; off >>= 1) m = fmax(m, __shfl_xor(m, off, 32));
          double e = (c < NC) ? exp(z - m) : 0.0;
          double S = e;
#pragma unroll
          for (int off = 16; off >= 1; off >>= 1) S += __shfl_xor(S, off, 32);
          double term = (c < NC) ? (0.05 * (double)c) * (e / S) : 0.0;
#pragma unroll
          for (int off = 16; off >= 1; off >>= 1) term += __shfl_xor(term, off, 32);
          if (c == 0) agrp[g] = term;
          __threadfence_block();
        }

#pragma unroll
        for (int u = 0; u < 8; ++u) {
          int n = lane + (u << 6);
          if (n < NNOD) {
            double kn = (double)kfS[n];
            double agn = agrp[n];
            double an;
            if (n == 0) an = agn;
            else an = kn * agrp[(n - 1) >> 1] + (1.0 - kn) * agn;
            areg[u] = an;
            anode[n] = an;
          }
        }
        __threadfence_block();

        double bv = -1e300; int bi = 0x7fffffff;
#pragma unroll
        for (int u = 0; u < 8; ++u) {
          int n = lane + (u << 6);
          if (n < NNOD) {
            double ap = (n == 0) ? 1.0 : anode[(n - 1) >> 1];
            double vi = areg[u] - ap;
            if (vi > bv) { bv = vi; bi = n; }
          }
        }
#pragma unroll
        for (int off = 32; off >= 1; off >>= 1) {
          double ov = __shfl_xor(bv, off, 64);
          int oi = __shfl_xor(bi, off, 64);
          if (ov > bv || (ov == bv && oi < bi)) { bv = ov; bi = oi; }
        }

        bool cond = (bv <= 1e-8) && (bi > 0);
        if (!cond || iter == 511) break;
        t = bi; p = (t - 1) >> 1;
        if (lane == 0) kfS[t] += 1.0f;
        __threadfence_block();
        ++iter;
      }

#pragma unroll
      for (int u = 0; u < 8; ++u) {
        int n = lane + (u << 6);
        if (n < NNOD) a_node[n] = areg[u];
      }
    }
  } else {
    // blocks 1..511: precompute q-walk for row b=bid (round-6 k_out, walk part)
    const int b = bid;
    float* col = (float*)smraw;
    if (tid < NSPL) col[tid] = qsT[tid * BATCH + b];
    __syncthreads();
    {
      int n = tid;                       // 0..255 < NNOD
      float q = 1.0f;
      int a = n;
      while (a > 0) {
        int p = (a - 1) >> 1;
        float v = col[p];
        q = fminf(q, (a & 1) ? -v : v);
        a = p;
      }
      q0 = q;
    }
    {
      int n = tid + 256;
      if (n < NNOD) {
        float q = 1.0f;
        int a = n;
        while (a > 0) {
          int p = (a - 1) >> 1;
          float v = col[p];
          q = fminf(q, (a & 1) ? -v : v);
          a = p;
        }
        q1 = q;
      }
    }
  }
  grid_bar(bar, 3, bid, tid);

  // ===== P5: clip + store (round-6 k_out, clip part) =====
  if (bid == 0) {
    // row 0, full walk (block 0 was busy scanning during P4)
    float* col = (float*)smraw;
    if (tid < NSPL) col[tid] = qsT[tid * BATCH + 0];
    __syncthreads();
#pragma unroll
    for (int rep = 0; rep < 2; ++rep) {
      int n = tid + rep * 256;
      if (n < NNOD) {
        float q = 1.0f;
        int a = n;
        while (a > 0) {
          int p = (a - 1) >> 1;
          float v = col[p];
          q = fminf(q, (a & 1) ? -v : v);
          a = p;
        }
        double r = fmin(fmax((double)q, 0.0), a_node[n]);
        out[(size_t)0 * NNOD + n] = (float)r;
      }
    }
  } else {
    const int b = bid;
    {
      int n = tid;
      double r = fmin(fmax((double)q0, 0.0), a_node[n]);
      out[(size_t)b * NNOD + n] = (float)r;
    }
    {
      int n = tid + 256;
      if (n < NNOD) {
        double r = fmin(fmax((double)q1, 0.0), a_node[n]);
        out[(size_t)b * NNOD + n] = (float)r;
      }
    }
  }
}

// ---------------------------------------------------------------------------
// Fallback chain (small-workspace only) — validated round-6 kernels, unchanged.
// ---------------------------------------------------------------------------
__global__ __launch_bounds__(256) void k_qsplitT_fb(const float* __restrict__ x,
                                                    const float* __restrict__ W,
                                                    const float* __restrict__ bias,
                                                    float* __restrict__ qsT) {
  const int s = threadIdx.x;
  const int b0 = blockIdx.x * 8;
  if (s >= NSPL) return;
  float acc0[8], acc1[8];
#pragma unroll
  for (int i = 0; i < 8; ++i) { acc0[i] = 0.f; acc1[i] = 0.f; }
#pragma unroll 2
  for (int f = 0; f < 256; ++f) {
    float w0 = W[f * NSPL + s];
    float w1 = W[(f + 256) * NSPL + s];
#pragma unroll
    for (int i = 0; i < 8; ++i) {
      acc0[i] += x[(b0 + i) * FDIM + f] * w0;
      acc1[i] += x[(b0 + i) * FDIM + f + 256] * w1;
    }
  }
  float bs = bias[s];
#pragma unroll
  for (int i = 0; i < 8; ++i) qsT[s * BATCH + b0 + i] = (acc0[i] + acc1[i]) + bs;
}

__global__ __launch_bounds__(256) void k_ga_fb(const float* __restrict__ qsT,
                                               float* __restrict__ ga,
                                               double* __restrict__ agrp0) {
  const int n = blockIdx.x;
  const int tid = threadIdx.x;
  __shared__ float qs[BATCH];
  __shared__ double part[4][NC];
  __shared__ float gaRow[NC];
#pragma unroll
  for (int rep = 0; rep < 2; ++rep) {
    int b = tid + rep * 256;
    qs[b] = qnode_walk(qsT, n, b);
  }
  __syncthreads();
  if (tid < 4 * NC) {
    int c = tid % NC, chunk = tid / NC;
    double ac = 0.05 * (double)c;
    double ssum = 0.0;
    int b0 = chunk * 128;
    for (int b = b0; b < b0 + 128; ++b) {
      float qh = qs[b] + 0.5f;
      double dqh = (double)qh;
      if (ac <= dqh) { double d = ac - dqh; ssum += d * d; }
    }
    part[chunk][c] = ssum;
  }
  __syncthreads();
  if (tid < NC) {
    double ac = 0.05 * (double)tid;
    double ssum = ((part[0][tid] + part[1][tid]) + part[2][tid]) + part[3][tid];
    float gv = (float)(0.5 * ac * ac + 0.5 * ssum);
    ga[n * NC + tid] = gv;
    gaRow[tid] = gv;
  }
  __syncthreads();
  if (tid == 0) {
    double z[NC], m = -1e300;
#pragma unroll
    for (int c = 0; c < NC; ++c) { z[c] = -100.0 * (double)gaRow[c]; m = fmax(m, z[c]); }
    double S = 0.0;
#pragma unroll
    for (int c = 0; c < NC; ++c) { z[c] = exp(z[c] - m); S += z[c]; }
    double A = 0.0;
#pragma unroll
    for (int c = 0; c < NC; ++c) A += (0.05 * (double)c) * (z[c] / S);
    agrp0[n] = A;
  }
}

__global__ __launch_bounds__(64) void k_scan_fb(const float* __restrict__ ga_g,
                                                const double* __restrict__ agrp0,
                                                double* __restrict__ a_node_out) {
  __shared__ float gaS[NNOD * NC];
  __shared__ double agrp[512];
  __shared__ double anode[512];
  __shared__ float kfS[512];
  const int lane = threadIdx.x;
  {
    const float4* src = (const float4*)ga_g;
    float4* dst = (float4*)gaS;
    const int n4 = (NNOD * NC) / 4;
#pragma unroll 4
    for (int i = lane; i < n4; i += 64) dst[i] = src[i];
    if (lane < (NNOD * NC) - n4 * 4) gaS[n4 * 4 + lane] = ga_g[n4 * 4 + lane];
  }
  for (int i = lane; i < 512; i += 64) {
    agrp[i] = (i < NNOD) ? agrp0[i] : 0.0;
    anode[i] = 0.0;
    kfS[i] = 0.0f;
  }
  __syncthreads();
  int t = 0, p = 0;
  double areg[8];
  int iter = 0;
  for (;;) {
    if (iter > 0) {
      int j = lane >> 5, c = lane & 31;
      int g = j ? p : t;
      double z = -1e300;
      if (c < NC) {
        double acc = (1.0 - (double)kfS[g]) * (double)gaS[g * NC + c];
        int l = 2 * g + 1, r = 2 * g + 2;
        if (l < NNOD) acc = acc + (double)kfS[l] * (double)gaS[l * NC + c];
        if (r < NNOD) acc = acc + (double)kfS[r] * (double)gaS[r * NC + c];
        z = -100.0 * acc;
      }
      double m = z;
#pragma unroll
      for (int off = 16; off >= 1; off >>= 1) m = fmax(m, __shfl_xor(m, off, 32));
      double e = (c < NC) ? exp(z - m) : 0.0;
      double S = e;
#pragma unroll
      for (int off = 16; off >= 1; off >>= 1) S += __shfl_xor(S, off, 32);
      double term = (c < NC) ? (0.05 * (double)c) * (e / S) : 0.0;
#pragma unroll
      for (int off = 16; off >= 1; off >>= 1) term += __shfl_xor(term, off, 32);
      if (c == 0) agrp[g] = term;
      __syncthreads();
    }
#pragma unroll
    for (int u = 0; u < 8; ++u) {
      int n = lane + (u << 6);
      if (n < NNOD) {
        double kn = (double)kfS[n];
        double agn = agrp[n];
        double an;
        if (n == 0) an = agn;
        else an = kn * agrp[(n - 1) >> 1] + (1.0 - kn) * agn;
        areg[u] = an;
        anode[n] = an;
      }
    }
    __syncthreads();
    double bv = -1e300; int bi = 0x7fffffff;
#pragma unroll
    for (int u = 0; u < 8; ++u) {
      int n = lane + (u << 6);
      if (n < NNOD) {
        double ap = (n == 0) ? 1.0 : anode[(n - 1) >> 1];
        double vi = areg[u] - ap;
        if (vi > bv) { bv = vi; bi = n; }
      }
    }
#pragma unroll
    for (int off = 32; off >= 1; off >>= 1) {
      double ov = __shfl_xor(bv, off, 64);
      int oi = __shfl_xor(bi, off, 64);
      if (ov > bv || (ov == bv && oi < bi)) { bv = ov; bi = oi; }
    }
    bool cond = (bv <= 1e-8) && (bi > 0);
    if (!cond || iter == 511) break;
    t = bi; p = (t - 1) >> 1;
    if (lane == 0) kfS[t] += 1.0f;
    __syncthreads();
    ++iter;
  }
#pragma unroll
  for (int u = 0; u < 8; ++u) {
    int n = lane + (u << 6);
    if (n < NNOD) a_node_out[n] = areg[u];
  }
}

__global__ __launch_bounds__(256) void k_out_fb(const float* __restrict__ qsT,
                                                const double* __restrict__ a_node,
                                                float* __restrict__ out) {
  __shared__ float col[NSPL];
  const int b = blockIdx.x;
  const int tid = threadIdx.x;
  if (tid < NSPL) col[tid] = qsT[tid * BATCH + b];
  __syncthreads();
#pragma unroll
  for (int rep = 0; rep < 2; ++rep) {
    int n = tid + rep * 256;
    if (n < NNOD) {
      float q = 1.0f;
      int a = n;
      while (a > 0) {
        int p = (a - 1) >> 1;
        float v = col[p];
        q = fminf(q, (a & 1) ? -v : v);
        a = p;
      }
      double r = fmin(fmax((double)q, 0.0), a_node[n]);
      out[(size_t)b * NNOD + n] = (float)r;
    }
  }
}

// ---------------------------------------------------------------------------
extern "C" void kernel_launch(void* const* d_in, const int* in_sizes, int n_in,
                              void* d_out, int out_size, void* d_ws, size_t ws_size,
                              hipStream_t stream) {
  (void)in_sizes; (void)n_in; (void)out_size;
  const float* x    = (const float*)d_in[0];
  const float* W    = (const float*)d_in[1];
  const float* bias = (const float*)d_in[2];
  float* out = (float*)d_out;

  char* ws = (char*)d_ws;
  const size_t PART_STRIDE = 256 * BATCH * sizeof(float);   // 524288 B per chunk
  const size_t BAR_BYTES = 8192;
  const size_t TAIL = 575488 + BAR_BYTES;                    // qsT+ga+agrp0+a_node+bar

  int n = 8;
  while (n > 1 && (size_t)n * PART_STRIDE + TAIL > ws_size) n >>= 1;
  bool splitk_ok = ((size_t)n * PART_STRIDE + TAIL <= ws_size);

  size_t P = splitk_ok ? (size_t)n * PART_STRIDE : 0;
  float*    qsT    = (float*)   (ws + P);
  float*    ga     = (float*)   (ws + P + 524288);
  double*   agrp0  = (double*)  (ws + P + 567296);
  double*   a_node = (double*)  (ws + P + 571392);
  unsigned* bar    = (unsigned*)(ws + P + 575488);

  if (splitk_ok) {
    float* partial = (float*)ws;
    hipMemsetAsync(bar, 0, BAR_BYTES, stream);   // barrier state: guaranteed zeros, poison-proof
    k_mega<<<dim3(512), dim3(256), 0, stream>>>(x, W, bias, partial, qsT, ga,
                                                agrp0, a_node, out, bar, 512 / n, n);
  } else {
    k_qsplitT_fb<<<dim3(64), dim3(256), 0, stream>>>(x, W, bias, qsT);
    k_ga_fb<<<dim3(NNOD), dim3(256), 0, stream>>>(qsT, ga, agrp0);
    k_scan_fb<<<dim3(1), dim3(64), 0, stream>>>(ga, agrp0, a_node);
    k_out_fb<<<dim3(BATCH), dim3(256), 0, stream>>>(qsT, a_node, out);
  }
}

// Round 8
// 199.150 us; speedup vs baseline: 1.4758x; 1.4758x over previous
//
#include <hip/hip_runtime.h>
#include <hip/hip_bf16.h>
#include <math.h>

// Sizes fixed by the reference setup: B=512, F=512, max_depth=8 -> S=255 splits, N=511 nodes, NC=21.
#define BATCH 512
#define FDIM  512
#define NSPL  255
#define NNOD  511
#define NC    21

// KNIFE-EDGE LEDGER (rounds 3,5,7): the scan trajectory depends on exact f64
// bits of qsT -> ga -> agrp0 and on the scan's own compiled FP sequence.
// Broke it: (r3) rewriting blend expressions; (r5) DPP/swizzle butterflies;
// (r7) scan compiled inside a merged function with fence substitution.
// Held bits: textually-identical kernel FUNCTIONS recompiled (r2->4->6),
// memory-path-only changes, downstream-of-scan changes (r6).
// This round: k_front merges gemm/reduce/ga (textual copies, __syncthreads
// kept) with grid barriers; k_scan and k_out are VERBATIM round-6 functions.

// ---------------------------------------------------------------------------
// Grid barrier (validated in round 7): hierarchical, state zeroed by
// hipMemsetAsync. slot(i)=bar+i*32. cells 1..16 (k*8+cell), root 33..34,
// gen 37..38. 512 blocks -> 64 arrivals/cell, 8 cells.
// ---------------------------------------------------------------------------
__device__ __forceinline__ unsigned* bslot(unsigned* bar, int i) { return bar + (size_t)i * 32; }

__device__ __forceinline__ void grid_bar(unsigned* bar, int k, int bid, int tid) {
  __syncthreads();
  if (tid == 0) {
    __threadfence();
    unsigned cell = (unsigned)(bid & 7);
    unsigned v = __hip_atomic_fetch_add(bslot(bar, 1 + k * 8 + (int)cell), 1u,
                                        __ATOMIC_ACQ_REL, __HIP_MEMORY_SCOPE_AGENT);
    if (v == 63u) {
      unsigned r = __hip_atomic_fetch_add(bslot(bar, 33 + k), 1u,
                                          __ATOMIC_ACQ_REL, __HIP_MEMORY_SCOPE_AGENT);
      if (r == 7u)
        __hip_atomic_store(bslot(bar, 37 + k), 1u, __ATOMIC_RELEASE, __HIP_MEMORY_SCOPE_AGENT);
    }
    while (__hip_atomic_load(bslot(bar, 37 + k), __ATOMIC_ACQUIRE, __HIP_MEMORY_SCOPE_AGENT) != 1u)
      __builtin_amdgcn_s_sleep(2);
    __threadfence();
  }
  __syncthreads();
}

// ---------------------------------------------------------------------------
// q_node walk (same bit pattern everywhere)
// ---------------------------------------------------------------------------
__device__ __forceinline__ float qnode_walk(const float* __restrict__ qsT, int n, int b) {
  float q = 1.0f;
  int a = n;
  while (a > 0) {
    int p = (a - 1) >> 1;
    float v = qsT[p * BATCH + b];
    q = fminf(q, (a & 1) ? -v : v);
    a = p;
  }
  return q;
}

// ---------------------------------------------------------------------------
// k_front: gemm -> bar0 -> reduce -> bar1 -> ga+agrp0. 512 blocks x 256.
// Every phase body is a textual copy of the validated round-6 kernels; all
// intra-block syncs are __syncthreads (no fence substitutions).
// LDS arena 34816 B (gemm tiles) -> 4 blocks/CU by LDS; (256,2) -> 2/CU by
// VGPR cap; 512 blocks co-resident on 256 CUs.
// ---------------------------------------------------------------------------
__global__ __launch_bounds__(256, 2) void k_front(
    const float* __restrict__ x, const float* __restrict__ W,
    const float* __restrict__ bias,
    float* __restrict__ partial, float* __restrict__ qsT,
    float* __restrict__ ga, double* __restrict__ agrp0,
    unsigned* __restrict__ bar, int fpc, int nchunks) {
  __shared__ __align__(16) char smraw[34816];
  const int tid = threadIdx.x;
  const int bid = blockIdx.x;

  // ===== P1: split-K GEMM (textual copy of validated k_qgemm) =====
  if (bid < 32 * nchunks) {
    float* Ws = (float*)smraw;
    float* xT = Ws + 64 * 68;
    const int s0 = (bid & 3) * 64;
    const int b0 = ((bid >> 2) & 7) * 64;
    const int bz = bid >> 5;
    const int f0 = bz * fpc;
    const int sx = tid & 15;
    const int by = tid >> 4;
    float acc[4][4];
#pragma unroll
    for (int i = 0; i < 4; ++i)
#pragma unroll
      for (int j = 0; j < 4; ++j) acc[i][j] = 0.f;

    for (int fc = f0; fc < f0 + fpc; fc += 64) {
      {
        int si = tid & 63, fr = tid >> 6;
#pragma unroll
        for (int r = 0; r < 16; ++r) {
          int fi = fr + r * 4;
          int s = s0 + si;
          Ws[fi * 68 + si] = (s < NSPL) ? W[(fc + fi) * NSPL + s] : 0.f;
        }
        int j = tid & 63, ir = tid >> 6;
#pragma unroll
        for (int r = 0; r < 16; ++r) {
          int i = ir + r * 4;
          xT[j * 68 + i] = x[(b0 + i) * FDIM + (fc + j)];
        }
      }
      __syncthreads();
#pragma unroll 8
      for (int f = 0; f < 64; ++f) {
        float4 av = *(const float4*)&Ws[f * 68 + sx * 4];
        float4 xv = *(const float4*)&xT[f * 68 + by * 4];
        const float a4[4] = {av.x, av.y, av.z, av.w};
        const float x4[4] = {xv.x, xv.y, xv.z, xv.w};
#pragma unroll
        for (int i = 0; i < 4; ++i)
#pragma unroll
          for (int j = 0; j < 4; ++j) acc[i][j] += a4[i] * x4[j];
      }
      __syncthreads();
    }

    float* pout = partial + (size_t)bz * (256 * BATCH);
#pragma unroll
    for (int i = 0; i < 4; ++i) {
      int s = s0 + sx * 4 + i;
      if (s < NSPL) {
        float4 v = make_float4(acc[i][0], acc[i][1], acc[i][2], acc[i][3]);
        *(float4*)&pout[s * BATCH + b0 + by * 4] = v;
      }
    }
  }
  grid_bar(bar, 0, bid, tid);

  // ===== P2: reduce (textual copy of validated k_qreduce) =====
  if (bid < 510) {
    int idx = bid * 256 + tid;
    if (idx < NSPL * BATCH) {
      int s = idx >> 9;
      float v = 0.f;
      for (int c = 0; c < nchunks; ++c) v += partial[(size_t)c * (256 * BATCH) + idx];
      qsT[idx] = v + bias[s];
    }
  }
  grid_bar(bar, 1, bid, tid);

  // ===== P3: g_a + agrp0 (textual copy of validated fused k_ga) =====
  if (bid < NNOD) {
    const int n = bid;
    float* qs = (float*)smraw;                              // 2048 B
    double (*part)[NC] = (double (*)[NC])(smraw + 2048);    // 672 B
    float* gaRow = (float*)(smraw + 2720);                  // 84 B
#pragma unroll
    for (int rep = 0; rep < 2; ++rep) {
      int b = tid + rep * 256;
      qs[b] = qnode_walk(qsT, n, b);
    }
    __syncthreads();
    if (tid < 4 * NC) {
      int c = tid % NC, chunk = tid / NC;
      double ac = 0.05 * (double)c;
      double ssum = 0.0;
      int b0 = chunk * 128;
      for (int b = b0; b < b0 + 128; ++b) {
        float qh = qs[b] + 0.5f;          // f32 add (NumPy scalar promotion keeps f32)
        double dqh = (double)qh;
        if (ac <= dqh) { double d = ac - dqh; ssum += d * d; }
      }
      part[chunk][c] = ssum;
    }
    __syncthreads();
    if (tid < NC) {
      double ac = 0.05 * (double)tid;
      double ssum = ((part[0][tid] + part[1][tid]) + part[2][tid]) + part[3][tid];
      float gv = (float)(0.5 * ac * ac + 0.5 * ssum);
      ga[n * NC + tid] = gv;
      gaRow[tid] = gv;
    }
    __syncthreads();
    if (tid == 0) {
      double z[NC], m = -1e300;
#pragma unroll
      for (int c = 0; c < NC; ++c) { z[c] = -100.0 * (double)gaRow[c]; m = fmax(m, z[c]); }
      double S = 0.0;
#pragma unroll
      for (int c = 0; c < NC; ++c) { z[c] = exp(z[c] - m); S += z[c]; }
      double A = 0.0;
#pragma unroll
      for (int c = 0; c < NC; ++c) A += (0.05 * (double)c) * (z[c] / S);
      agrp0[n] = A;
    }
  }
}

// ---------------------------------------------------------------------------
// k_scan — VERBATIM round-6 validated kernel function. Do not touch.
// ---------------------------------------------------------------------------
__global__ __launch_bounds__(64) void k_scan(const float* __restrict__ ga_g,
                                             const double* __restrict__ agrp0,
                                             double* __restrict__ a_node_out) {
  __shared__ float gaS[NNOD * NC];        // 42924 B
  __shared__ double agrp[512];            // 4096 B
  __shared__ double anode[512];           // 4096 B
  __shared__ float kfS[512];              // 2048 B
  const int lane = threadIdx.x;

  {
    const float4* src = (const float4*)ga_g;
    float4* dst = (float4*)gaS;
    const int n4 = (NNOD * NC) / 4;       // 2682
#pragma unroll 4
    for (int i = lane; i < n4; i += 64) dst[i] = src[i];
    if (lane < (NNOD * NC) - n4 * 4) gaS[n4 * 4 + lane] = ga_g[n4 * 4 + lane];
  }
  for (int i = lane; i < 512; i += 64) {
    agrp[i] = (i < NNOD) ? agrp0[i] : 0.0;
    anode[i] = 0.0;
    kfS[i] = 0.0f;
  }
  __syncthreads();

  int t = 0, p = 0;
  double areg[8];
  int iter = 0;
  for (;;) {
    if (iter > 0) {
      int j = lane >> 5, c = lane & 31;
      int g = j ? p : t;
      double z = -1e300;
      if (c < NC) {
        double acc = (1.0 - (double)kfS[g]) * (double)gaS[g * NC + c];
        int l = 2 * g + 1, r = 2 * g + 2;
        if (l < NNOD) acc = acc + (double)kfS[l] * (double)gaS[l * NC + c];
        if (r < NNOD) acc = acc + (double)kfS[r] * (double)gaS[r * NC + c];
        z = -100.0 * acc;
      }
      double m = z;
#pragma unroll
      for (int off = 16; off >= 1; off >>= 1) m = fmax(m, __shfl_xor(m, off, 32));
      double e = (c < NC) ? exp(z - m) : 0.0;
      double S = e;
#pragma unroll
      for (int off = 16; off >= 1; off >>= 1) S += __shfl_xor(S, off, 32);
      double term = (c < NC) ? (0.05 * (double)c) * (e / S) : 0.0;
#pragma unroll
      for (int off = 16; off >= 1; off >>= 1) term += __shfl_xor(term, off, 32);
      if (c == 0) agrp[g] = term;
      __syncthreads();
    }

#pragma unroll
    for (int u = 0; u < 8; ++u) {
      int n = lane + (u << 6);
      if (n < NNOD) {
        double kn = (double)kfS[n];
        double agn = agrp[n];
        double an;
        if (n == 0) an = agn;
        else an = kn * agrp[(n - 1) >> 1] + (1.0 - kn) * agn;
        areg[u] = an;
        anode[n] = an;
      }
    }
    __syncthreads();

    double bv = -1e300; int bi = 0x7fffffff;
#pragma unroll
    for (int u = 0; u < 8; ++u) {
      int n = lane + (u << 6);
      if (n < NNOD) {
        double ap = (n == 0) ? 1.0 : anode[(n - 1) >> 1];
        double vi = areg[u] - ap;
        if (vi > bv) { bv = vi; bi = n; }
      }
    }
#pragma unroll
    for (int off = 32; off >= 1; off >>= 1) {
      double ov = __shfl_xor(bv, off, 64);
      int oi = __shfl_xor(bi, off, 64);
      if (ov > bv || (ov == bv && oi < bi)) { bv = ov; bi = oi; }
    }

    bool cond = (bv <= 1e-8) && (bi > 0);
    if (!cond || iter == 511) break;   // fixed point (exact) or last body
    t = bi; p = (t - 1) >> 1;
    if (lane == 0) kfS[t] += 1.0f;
    __syncthreads();
    ++iter;
  }

#pragma unroll
  for (int u = 0; u < 8; ++u) {
    int n = lane + (u << 6);
    if (n < NNOD) a_node_out[n] = areg[u];
  }
}

// ---------------------------------------------------------------------------
// k_out — VERBATIM round-6 validated kernel function (downstream of scan).
// ---------------------------------------------------------------------------
__global__ __launch_bounds__(256) void k_out(const float* __restrict__ qsT,
                                             const double* __restrict__ a_node,
                                             float* __restrict__ out) {
  __shared__ float col[NSPL];
  const int b = blockIdx.x;
  const int tid = threadIdx.x;
  if (tid < NSPL) col[tid] = qsT[tid * BATCH + b];
  __syncthreads();
#pragma unroll
  for (int rep = 0; rep < 2; ++rep) {
    int n = tid + rep * 256;
    if (n < NNOD) {
      float q = 1.0f;
      int a = n;
      while (a > 0) {
        int p = (a - 1) >> 1;
        float v = col[p];
        q = fminf(q, (a & 1) ? -v : v);
        a = p;
      }
      double r = fmin(fmax((double)q, 0.0), a_node[n]);
      out[(size_t)b * NNOD + n] = (float)r;
    }
  }
}

// ---------------------------------------------------------------------------
// Fallback chain (small workspace) — validated round-6 kernels.
// ---------------------------------------------------------------------------
__global__ __launch_bounds__(256) void k_qsplitT_fb(const float* __restrict__ x,
                                                    const float* __restrict__ W,
                                                    const float* __restrict__ bias,
                                                    float* __restrict__ qsT) {
  const int s = threadIdx.x;
  const int b0 = blockIdx.x * 8;
  if (s >= NSPL) return;
  float acc0[8], acc1[8];
#pragma unroll
  for (int i = 0; i < 8; ++i) { acc0[i] = 0.f; acc1[i] = 0.f; }
#pragma unroll 2
  for (int f = 0; f < 256; ++f) {
    float w0 = W[f * NSPL + s];
    float w1 = W[(f + 256) * NSPL + s];
#pragma unroll
    for (int i = 0; i < 8; ++i) {
      acc0[i] += x[(b0 + i) * FDIM + f] * w0;
      acc1[i] += x[(b0 + i) * FDIM + f + 256] * w1;
    }
  }
  float bs = bias[s];
#pragma unroll
  for (int i = 0; i < 8; ++i) qsT[s * BATCH + b0 + i] = (acc0[i] + acc1[i]) + bs;
}

__global__ __launch_bounds__(256) void k_ga_fb(const float* __restrict__ qsT,
                                               float* __restrict__ ga,
                                               double* __restrict__ agrp0) {
  const int n = blockIdx.x;
  const int tid = threadIdx.x;
  __shared__ float qs[BATCH];
  __shared__ double part[4][NC];
  __shared__ float gaRow[NC];
#pragma unroll
  for (int rep = 0; rep < 2; ++rep) {
    int b = tid + rep * 256;
    qs[b] = qnode_walk(qsT, n, b);
  }
  __syncthreads();
  if (tid < 4 * NC) {
    int c = tid % NC, chunk = tid / NC;
    double ac = 0.05 * (double)c;
    double ssum = 0.0;
    int b0 = chunk * 128;
    for (int b = b0; b < b0 + 128; ++b) {
      float qh = qs[b] + 0.5f;
      double dqh = (double)qh;
      if (ac <= dqh) { double d = ac - dqh; ssum += d * d; }
    }
    part[chunk][c] = ssum;
  }
  __syncthreads();
  if (tid < NC) {
    double ac = 0.05 * (double)tid;
    double ssum = ((part[0][tid] + part[1][tid]) + part[2][tid]) + part[3][tid];
    float gv = (float)(0.5 * ac * ac + 0.5 * ssum);
    ga[n * NC + tid] = gv;
    gaRow[tid] = gv;
  }
  __syncthreads();
  if (tid == 0) {
    double z[NC], m = -1e300;
#pragma unroll
    for (int c = 0; c < NC; ++c) { z[c] = -100.0 * (double)gaRow[c]; m = fmax(m, z[c]); }
    double S = 0.0;
#pragma unroll
    for (int c = 0; c < NC; ++c) { z[c] = exp(z[c] - m); S += z[c]; }
    double A = 0.0;
#pragma unroll
    for (int c = 0; c < NC; ++c) A += (0.05 * (double)c) * (z[c] / S);
    agrp0[n] = A;
  }
}

// ---------------------------------------------------------------------------
extern "C" void kernel_launch(void* const* d_in, const int* in_sizes, int n_in,
                              void* d_out, int out_size, void* d_ws, size_t ws_size,
                              hipStream_t stream) {
  (void)in_sizes; (void)n_in; (void)out_size;
  const float* x    = (const float*)d_in[0];
  const float* W    = (const float*)d_in[1];
  const float* bias = (const float*)d_in[2];
  float* out = (float*)d_out;

  char* ws = (char*)d_ws;
  const size_t PART_STRIDE = 256 * BATCH * sizeof(float);   // 524288 B per chunk
  const size_t BAR_BYTES = 8192;
  const size_t TAIL = 575488 + BAR_BYTES;

  int n = 8;
  while (n > 1 && (size_t)n * PART_STRIDE + TAIL > ws_size) n >>= 1;
  bool merged_ok = ((size_t)8 * PART_STRIDE + TAIL <= ws_size);  // merged path needs full split-K=8

  size_t P = (size_t)n * PART_STRIDE;
  if (!merged_ok && (P + TAIL > ws_size)) P = 0;
  float*    qsT    = (float*)   (ws + P);
  float*    ga     = (float*)   (ws + P + 524288);
  double*   agrp0  = (double*)  (ws + P + 567296);
  double*   a_node = (double*)  (ws + P + 571392);
  unsigned* bar    = (unsigned*)(ws + P + 575488);

  if (merged_ok) {
    float* partial = (float*)ws;
    hipMemsetAsync(bar, 0, BAR_BYTES, stream);   // barrier state: guaranteed zeros
    k_front<<<dim3(512), dim3(256), 0, stream>>>(x, W, bias, partial, qsT, ga,
                                                 agrp0, bar, 512 / 8, 8);
  } else {
    k_qsplitT_fb<<<dim3(64), dim3(256), 0, stream>>>(x, W, bias, qsT);
    k_ga_fb<<<dim3(NNOD), dim3(256), 0, stream>>>(qsT, ga, agrp0);
  }
  k_scan<<<dim3(1), dim3(64), 0, stream>>>(ga, agrp0, a_node);
  k_out<<<dim3(BATCH), dim3(256), 0, stream>>>(qsT, a_node, out);
}

// Round 9
// 109.078 us; speedup vs baseline: 2.6944x; 1.8258x over previous
//
#include <hip/hip_runtime.h>
#include <hip/hip_bf16.h>
#include <math.h>

// Sizes fixed by the reference setup: B=512, F=512, max_depth=8 -> S=255 splits, N=511 nodes, NC=21.
#define BATCH 512
#define FDIM  512
#define NSPL  255
#define NNOD  511
#define NC    21

// KNIFE-EDGE LEDGER:
//  - Scan's own compiled FP/shuffle sequence is LOCKED (r3: expr rewrite broke
//    it; r5: DPP substitution broke it). k_scan below is verbatim round-6.
//  - Upstream qsT bit changes do NOT destabilize scan termination (r2: full
//    GEMM rewrite, scan still ~11 iters; output drift << tolerance).
//  - Custom grid barriers cost ~58 us EACH on this 8-XCD part (r7: 4 bars =
//    247us; r8: 2 bars = 131us). DEAD END — do not use spin barriers.
//  - Proven-safe change classes: textually-identical kernel functions
//    recompiled (r2/4/6), memory-path-only changes, downstream-of-scan (r6).
// This round: split-K folded into registers (acc[8][2][2]) with the EXACT
// validated combine order ((((0+p0)+p1)+...+p7)+bias) — deletes k_qreduce.

// ---------------------------------------------------------------------------
// Kernel 1 (fused split-K GEMM): qsT[s][b] = (sum_{c=0..7} P_c) + bias[s],
// P_c = sum_{f in chunk c, ascending} W[f,s]*x[b,f]  (per-chunk fmac chains
// and ascending combine exactly match the validated k_qgemm + k_qreduce).
// 32x32 tile, 256 threads, 2x2 micro. Grid (8 s-tiles, 16 b-tiles) = 128 blocks.
// LDS stride 34: inner-loop reads are broadcast/conflict-free; staging writes
// are 2-way (free) / 4-way (1.58x on 32 wave-writes, negligible).
// ---------------------------------------------------------------------------
__global__ __launch_bounds__(256) void k_qgemm(const float* __restrict__ x,
                                               const float* __restrict__ W,
                                               const float* __restrict__ bias,
                                               float* __restrict__ qsT) {
  __shared__ float Ws[64 * 34];   // [f][s]
  __shared__ float xT[64 * 34];   // [f][b]
  const int tid = threadIdx.x;
  const int s0 = blockIdx.x * 32;
  const int b0 = blockIdx.y * 32;
  const int sx = tid & 15;        // s = s0 + sx*2 + i
  const int by = tid >> 4;        // b = b0 + by*2 + j
  float acc[8][2][2];
#pragma unroll
  for (int c = 0; c < 8; ++c)
#pragma unroll
    for (int i = 0; i < 2; ++i)
#pragma unroll
      for (int j = 0; j < 2; ++j) acc[c][i][j] = 0.f;

#pragma unroll
  for (int c = 0; c < 8; ++c) {
    const int fc = c * 64;
    // stage W rows fc..fc+63, cols s0..s0+31 (guard s>=255 -> 0)
    {
      int si = tid & 31, fr = tid >> 5;
#pragma unroll
      for (int r = 0; r < 8; ++r) {
        int fi = fr + r * 8;
        int s = s0 + si;
        Ws[fi * 34 + si] = (s < NSPL) ? W[(fc + fi) * NSPL + s] : 0.f;
      }
      // stage x transposed: xT[f][b]; global read coalesced over f
      int j = tid & 63, ir = tid >> 6;
#pragma unroll
      for (int r = 0; r < 8; ++r) {
        int bb = ir + r * 4;
        xT[j * 34 + bb] = x[(b0 + bb) * FDIM + (fc + j)];
      }
    }
    __syncthreads();
#pragma unroll 8
    for (int f = 0; f < 64; ++f) {
      float2 av = *(const float2*)&Ws[f * 34 + sx * 2];
      float2 xv = *(const float2*)&xT[f * 34 + by * 2];
      acc[c][0][0] += av.x * xv.x;
      acc[c][0][1] += av.x * xv.y;
      acc[c][1][0] += av.y * xv.x;
      acc[c][1][1] += av.y * xv.y;
    }
    __syncthreads();
  }

  // combine: v = 0 + p0 + p1 + ... + p7 (ascending), then + bias — exactly
  // the validated k_qreduce fold.
#pragma unroll
  for (int i = 0; i < 2; ++i) {
    int s = s0 + sx * 2 + i;
    if (s < NSPL) {
      float bs = bias[s];
      float2 o;
      {
        float v = 0.f;
#pragma unroll
        for (int c = 0; c < 8; ++c) v += acc[c][i][0];
        o.x = v + bs;
      }
      {
        float v = 0.f;
#pragma unroll
        for (int c = 0; c < 8; ++c) v += acc[c][i][1];
        o.y = v + bs;
      }
      *(float2*)&qsT[s * BATCH + b0 + by * 2] = o;
    }
  }
}

// ---------------------------------------------------------------------------
// q_node walk (same bit pattern everywhere)
// ---------------------------------------------------------------------------
__device__ __forceinline__ float qnode_walk(const float* __restrict__ qsT, int n, int b) {
  float q = 1.0f;
  int a = n;
  while (a > 0) {
    int p = (a - 1) >> 1;
    float v = qsT[p * BATCH + b];
    q = fminf(q, (a & 1) ? -v : v);
    a = p;
  }
  return q;
}

// ---------------------------------------------------------------------------
// Kernel 2 — VERBATIM round-6 fused k_ga (g_a row + agrp0 softmin).
// ---------------------------------------------------------------------------
__global__ __launch_bounds__(256) void k_ga(const float* __restrict__ qsT,
                                            float* __restrict__ ga,
                                            double* __restrict__ agrp0) {
  const int n = blockIdx.x;
  const int tid = threadIdx.x;
  __shared__ float qs[BATCH];
  __shared__ double part[4][NC];
  __shared__ float gaRow[NC];
#pragma unroll
  for (int rep = 0; rep < 2; ++rep) {
    int b = tid + rep * 256;
    qs[b] = qnode_walk(qsT, n, b);
  }
  __syncthreads();
  if (tid < 4 * NC) {
    int c = tid % NC, chunk = tid / NC;
    double ac = 0.05 * (double)c;
    double ssum = 0.0;
    int b0 = chunk * 128;
    for (int b = b0; b < b0 + 128; ++b) {
      float qh = qs[b] + 0.5f;          // f32 add (NumPy scalar promotion keeps f32)
      double dqh = (double)qh;
      if (ac <= dqh) { double d = ac - dqh; ssum += d * d; }
    }
    part[chunk][c] = ssum;
  }
  __syncthreads();
  if (tid < NC) {
    double ac = 0.05 * (double)tid;
    double ssum = ((part[0][tid] + part[1][tid]) + part[2][tid]) + part[3][tid];
    float gv = (float)(0.5 * ac * ac + 0.5 * ssum);
    ga[n * NC + tid] = gv;
    gaRow[tid] = gv;
  }
  __syncthreads();
  if (tid == 0) {
    double z[NC], m = -1e300;
#pragma unroll
    for (int c = 0; c < NC; ++c) { z[c] = -100.0 * (double)gaRow[c]; m = fmax(m, z[c]); }
    double S = 0.0;
#pragma unroll
    for (int c = 0; c < NC; ++c) { z[c] = exp(z[c] - m); S += z[c]; }
    double A = 0.0;
#pragma unroll
    for (int c = 0; c < NC; ++c) A += (0.05 * (double)c) * (z[c] / S);
    agrp0[n] = A;
  }
}

// ---------------------------------------------------------------------------
// Kernel 3 — VERBATIM round-6 k_scan. Do not touch.
// ---------------------------------------------------------------------------
__global__ __launch_bounds__(64) void k_scan(const float* __restrict__ ga_g,
                                             const double* __restrict__ agrp0,
                                             double* __restrict__ a_node_out) {
  __shared__ float gaS[NNOD * NC];        // 42924 B
  __shared__ double agrp[512];            // 4096 B
  __shared__ double anode[512];           // 4096 B
  __shared__ float kfS[512];              // 2048 B
  const int lane = threadIdx.x;

  {
    const float4* src = (const float4*)ga_g;
    float4* dst = (float4*)gaS;
    const int n4 = (NNOD * NC) / 4;       // 2682
#pragma unroll 4
    for (int i = lane; i < n4; i += 64) dst[i] = src[i];
    if (lane < (NNOD * NC) - n4 * 4) gaS[n4 * 4 + lane] = ga_g[n4 * 4 + lane];
  }
  for (int i = lane; i < 512; i += 64) {
    agrp[i] = (i < NNOD) ? agrp0[i] : 0.0;
    anode[i] = 0.0;
    kfS[i] = 0.0f;
  }
  __syncthreads();

  int t = 0, p = 0;
  double areg[8];
  int iter = 0;
  for (;;) {
    if (iter > 0) {
      int j = lane >> 5, c = lane & 31;
      int g = j ? p : t;
      double z = -1e300;
      if (c < NC) {
        double acc = (1.0 - (double)kfS[g]) * (double)gaS[g * NC + c];
        int l = 2 * g + 1, r = 2 * g + 2;
        if (l < NNOD) acc = acc + (double)kfS[l] * (double)gaS[l * NC + c];
        if (r < NNOD) acc = acc + (double)kfS[r] * (double)gaS[r * NC + c];
        z = -100.0 * acc;
      }
      double m = z;
#pragma unroll
      for (int off = 16; off >= 1; off >>= 1) m = fmax(m, __shfl_xor(m, off, 32));
      double e = (c < NC) ? exp(z - m) : 0.0;
      double S = e;
#pragma unroll
      for (int off = 16; off >= 1; off >>= 1) S += __shfl_xor(S, off, 32);
      double term = (c < NC) ? (0.05 * (double)c) * (e / S) : 0.0;
#pragma unroll
      for (int off = 16; off >= 1; off >>= 1) term += __shfl_xor(term, off, 32);
      if (c == 0) agrp[g] = term;
      __syncthreads();
    }

#pragma unroll
    for (int u = 0; u < 8; ++u) {
      int n = lane + (u << 6);
      if (n < NNOD) {
        double kn = (double)kfS[n];
        double agn = agrp[n];
        double an;
        if (n == 0) an = agn;
        else an = kn * agrp[(n - 1) >> 1] + (1.0 - kn) * agn;
        areg[u] = an;
        anode[n] = an;
      }
    }
    __syncthreads();

    double bv = -1e300; int bi = 0x7fffffff;
#pragma unroll
    for (int u = 0; u < 8; ++u) {
      int n = lane + (u << 6);
      if (n < NNOD) {
        double ap = (n == 0) ? 1.0 : anode[(n - 1) >> 1];
        double vi = areg[u] - ap;
        if (vi > bv) { bv = vi; bi = n; }
      }
    }
#pragma unroll
    for (int off = 32; off >= 1; off >>= 1) {
      double ov = __shfl_xor(bv, off, 64);
      int oi = __shfl_xor(bi, off, 64);
      if (ov > bv || (ov == bv && oi < bi)) { bv = ov; bi = oi; }
    }

    bool cond = (bv <= 1e-8) && (bi > 0);
    if (!cond || iter == 511) break;   // fixed point (exact) or last body
    t = bi; p = (t - 1) >> 1;
    if (lane == 0) kfS[t] += 1.0f;
    __syncthreads();
    ++iter;
  }

#pragma unroll
  for (int u = 0; u < 8; ++u) {
    int n = lane + (u << 6);
    if (n < NNOD) a_node_out[n] = areg[u];
  }
}

// ---------------------------------------------------------------------------
// Kernel 4 — VERBATIM round-6 k_out (downstream of scan).
// ---------------------------------------------------------------------------
__global__ __launch_bounds__(256) void k_out(const float* __restrict__ qsT,
                                             const double* __restrict__ a_node,
                                             float* __restrict__ out) {
  __shared__ float col[NSPL];
  const int b = blockIdx.x;
  const int tid = threadIdx.x;
  if (tid < NSPL) col[tid] = qsT[tid * BATCH + b];
  __syncthreads();
#pragma unroll
  for (int rep = 0; rep < 2; ++rep) {
    int n = tid + rep * 256;
    if (n < NNOD) {
      float q = 1.0f;
      int a = n;
      while (a > 0) {
        int p = (a - 1) >> 1;
        float v = col[p];
        q = fminf(q, (a & 1) ? -v : v);
        a = p;
      }
      double r = fmin(fmax((double)q, 0.0), a_node[n]);
      out[(size_t)b * NNOD + n] = (float)r;
    }
  }
}

// ---------------------------------------------------------------------------
extern "C" void kernel_launch(void* const* d_in, const int* in_sizes, int n_in,
                              void* d_out, int out_size, void* d_ws, size_t ws_size,
                              hipStream_t stream) {
  (void)in_sizes; (void)n_in; (void)out_size; (void)ws_size;
  const float* x    = (const float*)d_in[0];
  const float* W    = (const float*)d_in[1];
  const float* bias = (const float*)d_in[2];
  float* out = (float*)d_out;

  char* ws = (char*)d_ws;
  float*  qsT    = (float*) (ws + 0);        // 522240 B, pad to 524288
  float*  ga     = (float*) (ws + 524288);   // 42924 B, pad to 43008
  double* agrp0  = (double*)(ws + 567296);   // 4088 B
  double* a_node = (double*)(ws + 571392);   // 4088 B -> end 575480

  k_qgemm<<<dim3(8, 16), dim3(256), 0, stream>>>(x, W, bias, qsT);
  k_ga<<<dim3(NNOD), dim3(256), 0, stream>>>(qsT, ga, agrp0);
  k_scan<<<dim3(1), dim3(64), 0, stream>>>(ga, agrp0, a_node);
  k_out<<<dim3(BATCH), dim3(256), 0, stream>>>(qsT, a_node, out);
}

// Round 10
// 93.977 us; speedup vs baseline: 3.1274x; 1.1607x over previous
//
#include <hip/hip_runtime.h>
#include <hip/hip_bf16.h>
#include <math.h>

// Sizes fixed by the reference setup: B=512, F=512, max_depth=8 -> S=255 splits, N=511 nodes, NC=21.
#define BATCH 512
#define FDIM  512
#define NSPL  255
#define NNOD  511
#define NC    21

// KNIFE-EDGE LEDGER (final):
//  - k_scan's compiled FP/shuffle sequence is LOCKED. Broke 3x: r3 expr
//    rewrite, r5 DPP substitution, r7 merged-function+fence. Each blowup =
//    full 512 iterations (~900us) while still passing absmax. Verbatim only.
//  - Custom grid barriers cost ~58us EACH (r7: 4 bars=247us, r8: 2 bars=131us)
//    — agent-scope fence/L2-writeback on 8 XCDs. DEAD END.
//  - In-kernel GEMM fusion (r9): saved one ~3us launch, cost ~19us of kernel
//    time (poor reuse + latency-bound staging). DEAD END.
//  - Proven-safe classes: textually-identical kernel functions recompiled
//    (r2/4/6), memory-path-only changes w/ same FP op order (r6, this round's
//    float4 k_qreduce), downstream-of-scan changes (r6).
// This file = round-6 validated configuration (92.86us) + float4 k_qreduce.

// ---------------------------------------------------------------------------
// Kernel 1: tiled split-K GEMM (validated r2/r6). partial[z][s][b] =
// sum_{f in chunk z} W[f,s]*x[b,f]. 64x64 tile, 4x4 micro, grid (4,8,8)=256.
// ---------------------------------------------------------------------------
__global__ __launch_bounds__(256) void k_qgemm(const float* __restrict__ x,
                                               const float* __restrict__ W,
                                               float* __restrict__ partial,
                                               int fpc) {
  __shared__ float Ws[64 * 68];
  __shared__ float xT[64 * 68];
  const int tid = threadIdx.x;
  const int s0 = blockIdx.x * 64;
  const int b0 = blockIdx.y * 64;
  const int f0 = blockIdx.z * fpc;
  const int sx = tid & 15;
  const int by = tid >> 4;
  float acc[4][4];
#pragma unroll
  for (int i = 0; i < 4; ++i)
#pragma unroll
    for (int j = 0; j < 4; ++j) acc[i][j] = 0.f;

  for (int fc = f0; fc < f0 + fpc; fc += 64) {
    {
      int si = tid & 63, fr = tid >> 6;
#pragma unroll
      for (int r = 0; r < 16; ++r) {
        int fi = fr + r * 4;
        int s = s0 + si;
        Ws[fi * 68 + si] = (s < NSPL) ? W[(fc + fi) * NSPL + s] : 0.f;
      }
      int j = tid & 63, ir = tid >> 6;
#pragma unroll
      for (int r = 0; r < 16; ++r) {
        int i = ir + r * 4;
        xT[j * 68 + i] = x[(b0 + i) * FDIM + (fc + j)];
      }
    }
    __syncthreads();
#pragma unroll 8
    for (int f = 0; f < 64; ++f) {
      float4 av = *(const float4*)&Ws[f * 68 + sx * 4];
      float4 xv = *(const float4*)&xT[f * 68 + by * 4];
      const float a4[4] = {av.x, av.y, av.z, av.w};
      const float x4[4] = {xv.x, xv.y, xv.z, xv.w};
#pragma unroll
      for (int i = 0; i < 4; ++i)
#pragma unroll
        for (int j = 0; j < 4; ++j) acc[i][j] += a4[i] * x4[j];
    }
    __syncthreads();
  }

  float* pout = partial + (size_t)blockIdx.z * (256 * BATCH);
#pragma unroll
  for (int i = 0; i < 4; ++i) {
    int s = s0 + sx * 4 + i;
    if (s < NSPL) {
      float4 v = make_float4(acc[i][0], acc[i][1], acc[i][2], acc[i][3]);
      *(float4*)&pout[s * BATCH + b0 + by * 4] = v;
    }
  }
}

// ---------------------------------------------------------------------------
// Kernel 1b: reduce, float4-vectorized (bit-identical per-element op order:
// v = 0 + p0 + ... + p7 ascending, then + bias[s]; all 4 lanes of a float4
// share the same s because BATCH=512 is divisible by 4).
// ---------------------------------------------------------------------------
__global__ __launch_bounds__(256) void k_qreduce(const float* __restrict__ partial,
                                                 const float* __restrict__ bias,
                                                 float* __restrict__ qsT, int n) {
  int idx4 = blockIdx.x * 256 + threadIdx.x;
  if (idx4 >= (NSPL * BATCH) / 4) return;
  int s = (idx4 * 4) >> 9;
  float4 v = make_float4(0.f, 0.f, 0.f, 0.f);
  for (int c = 0; c < n; ++c) {
    float4 p = *(const float4*)&partial[(size_t)c * (256 * BATCH) + idx4 * 4];
    v.x += p.x; v.y += p.y; v.z += p.z; v.w += p.w;
  }
  float bs = bias[s];
  v.x += bs; v.y += bs; v.z += bs; v.w += bs;
  *(float4*)&qsT[idx4 * 4] = v;
}

// ---------------------------------------------------------------------------
// q_node walk (same bit pattern everywhere)
// ---------------------------------------------------------------------------
__device__ __forceinline__ float qnode_walk(const float* __restrict__ qsT, int n, int b) {
  float q = 1.0f;
  int a = n;
  while (a > 0) {
    int p = (a - 1) >> 1;
    float v = qsT[p * BATCH + b];
    q = fminf(q, (a & 1) ? -v : v);
    a = p;
  }
  return q;
}

// ---------------------------------------------------------------------------
// Kernel 2 — VERBATIM round-6 fused k_ga (g_a row + agrp0 softmin).
// ---------------------------------------------------------------------------
__global__ __launch_bounds__(256) void k_ga(const float* __restrict__ qsT,
                                            float* __restrict__ ga,
                                            double* __restrict__ agrp0) {
  const int n = blockIdx.x;
  const int tid = threadIdx.x;
  __shared__ float qs[BATCH];
  __shared__ double part[4][NC];
  __shared__ float gaRow[NC];
#pragma unroll
  for (int rep = 0; rep < 2; ++rep) {
    int b = tid + rep * 256;
    qs[b] = qnode_walk(qsT, n, b);
  }
  __syncthreads();
  if (tid < 4 * NC) {
    int c = tid % NC, chunk = tid / NC;
    double ac = 0.05 * (double)c;
    double ssum = 0.0;
    int b0 = chunk * 128;
    for (int b = b0; b < b0 + 128; ++b) {
      float qh = qs[b] + 0.5f;          // f32 add (NumPy scalar promotion keeps f32)
      double dqh = (double)qh;
      if (ac <= dqh) { double d = ac - dqh; ssum += d * d; }
    }
    part[chunk][c] = ssum;
  }
  __syncthreads();
  if (tid < NC) {
    double ac = 0.05 * (double)tid;
    double ssum = ((part[0][tid] + part[1][tid]) + part[2][tid]) + part[3][tid];
    float gv = (float)(0.5 * ac * ac + 0.5 * ssum);
    ga[n * NC + tid] = gv;
    gaRow[tid] = gv;
  }
  __syncthreads();
  if (tid == 0) {
    double z[NC], m = -1e300;
#pragma unroll
    for (int c = 0; c < NC; ++c) { z[c] = -100.0 * (double)gaRow[c]; m = fmax(m, z[c]); }
    double S = 0.0;
#pragma unroll
    for (int c = 0; c < NC; ++c) { z[c] = exp(z[c] - m); S += z[c]; }
    double A = 0.0;
#pragma unroll
    for (int c = 0; c < NC; ++c) A += (0.05 * (double)c) * (z[c] / S);
    agrp0[n] = A;
  }
}

// ---------------------------------------------------------------------------
// Kernel 3 — VERBATIM round-6 k_scan. LOCKED. Do not touch.
// ---------------------------------------------------------------------------
__global__ __launch_bounds__(64) void k_scan(const float* __restrict__ ga_g,
                                             const double* __restrict__ agrp0,
                                             double* __restrict__ a_node_out) {
  __shared__ float gaS[NNOD * NC];        // 42924 B
  __shared__ double agrp[512];            // 4096 B
  __shared__ double anode[512];           // 4096 B
  __shared__ float kfS[512];              // 2048 B
  const int lane = threadIdx.x;

  {
    const float4* src = (const float4*)ga_g;
    float4* dst = (float4*)gaS;
    const int n4 = (NNOD * NC) / 4;       // 2682
#pragma unroll 4
    for (int i = lane; i < n4; i += 64) dst[i] = src[i];
    if (lane < (NNOD * NC) - n4 * 4) gaS[n4 * 4 + lane] = ga_g[n4 * 4 + lane];
  }
  for (int i = lane; i < 512; i += 64) {
    agrp[i] = (i < NNOD) ? agrp0[i] : 0.0;
    anode[i] = 0.0;
    kfS[i] = 0.0f;
  }
  __syncthreads();

  int t = 0, p = 0;
  double areg[8];
  int iter = 0;
  for (;;) {
    if (iter > 0) {
      int j = lane >> 5, c = lane & 31;
      int g = j ? p : t;
      double z = -1e300;
      if (c < NC) {
        double acc = (1.0 - (double)kfS[g]) * (double)gaS[g * NC + c];
        int l = 2 * g + 1, r = 2 * g + 2;
        if (l < NNOD) acc = acc + (double)kfS[l] * (double)gaS[l * NC + c];
        if (r < NNOD) acc = acc + (double)kfS[r] * (double)gaS[r * NC + c];
        z = -100.0 * acc;
      }
      double m = z;
#pragma unroll
      for (int off = 16; off >= 1; off >>= 1) m = fmax(m, __shfl_xor(m, off, 32));
      double e = (c < NC) ? exp(z - m) : 0.0;
      double S = e;
#pragma unroll
      for (int off = 16; off >= 1; off >>= 1) S += __shfl_xor(S, off, 32);
      double term = (c < NC) ? (0.05 * (double)c) * (e / S) : 0.0;
#pragma unroll
      for (int off = 16; off >= 1; off >>= 1) term += __shfl_xor(term, off, 32);
      if (c == 0) agrp[g] = term;
      __syncthreads();
    }

#pragma unroll
    for (int u = 0; u < 8; ++u) {
      int n = lane + (u << 6);
      if (n < NNOD) {
        double kn = (double)kfS[n];
        double agn = agrp[n];
        double an;
        if (n == 0) an = agn;
        else an = kn * agrp[(n - 1) >> 1] + (1.0 - kn) * agn;
        areg[u] = an;
        anode[n] = an;
      }
    }
    __syncthreads();

    double bv = -1e300; int bi = 0x7fffffff;
#pragma unroll
    for (int u = 0; u < 8; ++u) {
      int n = lane + (u << 6);
      if (n < NNOD) {
        double ap = (n == 0) ? 1.0 : anode[(n - 1) >> 1];
        double vi = areg[u] - ap;
        if (vi > bv) { bv = vi; bi = n; }
      }
    }
#pragma unroll
    for (int off = 32; off >= 1; off >>= 1) {
      double ov = __shfl_xor(bv, off, 64);
      int oi = __shfl_xor(bi, off, 64);
      if (ov > bv || (ov == bv && oi < bi)) { bv = ov; bi = oi; }
    }

    bool cond = (bv <= 1e-8) && (bi > 0);
    if (!cond || iter == 511) break;   // fixed point (exact) or last body
    t = bi; p = (t - 1) >> 1;
    if (lane == 0) kfS[t] += 1.0f;
    __syncthreads();
    ++iter;
  }

#pragma unroll
  for (int u = 0; u < 8; ++u) {
    int n = lane + (u << 6);
    if (n < NNOD) a_node_out[n] = areg[u];
  }
}

// ---------------------------------------------------------------------------
// Kernel 4 — VERBATIM round-6 k_out (downstream of scan).
// ---------------------------------------------------------------------------
__global__ __launch_bounds__(256) void k_out(const float* __restrict__ qsT,
                                             const double* __restrict__ a_node,
                                             float* __restrict__ out) {
  __shared__ float col[NSPL];
  const int b = blockIdx.x;
  const int tid = threadIdx.x;
  if (tid < NSPL) col[tid] = qsT[tid * BATCH + b];
  __syncthreads();
#pragma unroll
  for (int rep = 0; rep < 2; ++rep) {
    int n = tid + rep * 256;
    if (n < NNOD) {
      float q = 1.0f;
      int a = n;
      while (a > 0) {
        int p = (a - 1) >> 1;
        float v = col[p];
        q = fminf(q, (a & 1) ? -v : v);
        a = p;
      }
      double r = fmin(fmax((double)q, 0.0), a_node[n]);
      out[(size_t)b * NNOD + n] = (float)r;
    }
  }
}

// ---------------------------------------------------------------------------
// Fallback GEMM (small workspace only) — validated.
// ---------------------------------------------------------------------------
__global__ __launch_bounds__(256) void k_qsplitT_fb(const float* __restrict__ x,
                                                    const float* __restrict__ W,
                                                    const float* __restrict__ bias,
                                                    float* __restrict__ qsT) {
  const int s = threadIdx.x;
  const int b0 = blockIdx.x * 8;
  if (s >= NSPL) return;
  float acc0[8], acc1[8];
#pragma unroll
  for (int i = 0; i < 8; ++i) { acc0[i] = 0.f; acc1[i] = 0.f; }
#pragma unroll 2
  for (int f = 0; f < 256; ++f) {
    float w0 = W[f * NSPL + s];
    float w1 = W[(f + 256) * NSPL + s];
#pragma unroll
    for (int i = 0; i < 8; ++i) {
      acc0[i] += x[(b0 + i) * FDIM + f] * w0;
      acc1[i] += x[(b0 + i) * FDIM + f + 256] * w1;
    }
  }
  float bs = bias[s];
#pragma unroll
  for (int i = 0; i < 8; ++i) qsT[s * BATCH + b0 + i] = (acc0[i] + acc1[i]) + bs;
}

// ---------------------------------------------------------------------------
extern "C" void kernel_launch(void* const* d_in, const int* in_sizes, int n_in,
                              void* d_out, int out_size, void* d_ws, size_t ws_size,
                              hipStream_t stream) {
  (void)in_sizes; (void)n_in; (void)out_size;
  const float* x    = (const float*)d_in[0];
  const float* W    = (const float*)d_in[1];
  const float* bias = (const float*)d_in[2];
  float* out = (float*)d_out;

  char* ws = (char*)d_ws;
  const size_t PART_STRIDE = 256 * BATCH * sizeof(float);   // 524288 B per chunk
  const size_t TAIL = 575488;                                // qsT+ga+agrp0+a_node (padded)

  int n = 8;
  while (n > 1 && (size_t)n * PART_STRIDE + TAIL > ws_size) n >>= 1;
  bool splitk_ok = ((size_t)n * PART_STRIDE + TAIL <= ws_size);

  size_t P = splitk_ok ? (size_t)n * PART_STRIDE : 0;
  float*  qsT    = (float*) (ws + P);
  float*  ga     = (float*) (ws + P + 524288);
  double* agrp0  = (double*)(ws + P + 567296);
  double* a_node = (double*)(ws + P + 571392);

  if (splitk_ok) {
    float* partial = (float*)ws;
    k_qgemm<<<dim3(4, 8, n), dim3(256), 0, stream>>>(x, W, partial, 512 / n);
    k_qreduce<<<dim3(128), dim3(256), 0, stream>>>(partial, bias, qsT, n);
  } else {
    k_qsplitT_fb<<<dim3(64), dim3(256), 0, stream>>>(x, W, bias, qsT);
  }
  k_ga<<<dim3(NNOD), dim3(256), 0, stream>>>(qsT, ga, agrp0);
  k_scan<<<dim3(1), dim3(64), 0, stream>>>(ga, agrp0, a_node);
  k_out<<<dim3(BATCH), dim3(256), 0, stream>>>(qsT, a_node, out);
}